// Round 1
// baseline (4518.653 us; speedup 1.0000x reference)
//
#include <hip/hip_runtime.h>
#include <cstdint>

#define F0 100
#define FH 128
#define FO 64
#define BN_EPS 1e-5f

static inline int ceil_div(long long a, long long b) { return (int)((a + b - 1) / b); }

// ---------------- degree / coefficient precompute ----------------

__global__ __launch_bounds__(256) void deg_count_kernel(const int* __restrict__ row,
                                                        int* __restrict__ deg, int E) {
  int e = blockIdx.x * blockDim.x + threadIdx.x;
  if (e < E) atomicAdd(&deg[row[e]], 1);
}

__global__ __launch_bounds__(256) void dinv_kernel(const int* __restrict__ deg,
                                                   float* __restrict__ dinv, int n) {
  int i = blockIdx.x * blockDim.x + threadIdx.x;
  if (i < n) {
    int d = deg[i];
    dinv[i] = (d > 0) ? rsqrtf((float)d) : 0.0f;
  }
}

__global__ __launch_bounds__(256) void coef_kernel(const int* __restrict__ row,
                                                   const int* __restrict__ col,
                                                   const float* __restrict__ ew,
                                                   const float* __restrict__ dinv,
                                                   float* __restrict__ coef, int E) {
  int e = blockIdx.x * blockDim.x + threadIdx.x;
  if (e < E) coef[e] = dinv[row[e]] * ew[e] * dinv[col[e]];
}

// ---------------- graph conv: out[col[e]] += coef[e] * x[row[e]] ----------------
// One thread per (edge, 4-feature group). float4 gather + 4 scalar HW f32 atomics.

template <int F>
__global__ __launch_bounds__(256) void conv_atomic_kernel(const float* __restrict__ x,
                                                          const int* __restrict__ row,
                                                          const int* __restrict__ col,
                                                          const float* __restrict__ coef,
                                                          float* __restrict__ out, int E) {
  constexpr int G = F / 4;
  long long idx = (long long)blockIdx.x * blockDim.x + threadIdx.x;
  if (idx >= (long long)E * G) return;
  int e = (int)(idx / G);
  int g = (int)(idx % G);
  float c = coef[e];
  int src = row[e];
  int dst = col[e];
  float4 xv = *reinterpret_cast<const float4*>(x + (size_t)src * F + g * 4);
  float* o = out + (size_t)dst * F + g * 4;
  unsafeAtomicAdd(o + 0, c * xv.x);
  unsafeAtomicAdd(o + 1, c * xv.y);
  unsafeAtomicAdd(o + 2, c * xv.z);
  unsafeAtomicAdd(o + 3, c * xv.w);
}

// ---------------- GEMM: out[n x FOUT] = A[n x K] @ W[K x FOUT] + bias ----------------

template <int K, int FOUT, int ROWS, int BK>
__global__ __launch_bounds__(256) void gemm_bias_kernel(const float* __restrict__ A,
                                                        const float* __restrict__ W,
                                                        const float* __restrict__ bias,
                                                        float* __restrict__ out, int n) {
  constexpr int TPR = 256 / ROWS;   // threads per row
  constexpr int CPT = FOUT / TPR;   // cols per thread (consecutive)
  __shared__ float sA[ROWS][BK];
  __shared__ float sB[BK][FOUT];

  int r = threadIdx.x / TPR;
  int c0 = (threadIdx.x % TPR) * CPT;
  int gr = blockIdx.x * ROWS + r;

  float acc[CPT];
#pragma unroll
  for (int j = 0; j < CPT; ++j) acc[j] = 0.0f;

  for (int k0 = 0; k0 < K; k0 += BK) {
    for (int i = threadIdx.x; i < ROWS * BK; i += 256) {
      int rr = i / BK, kk = i % BK;
      int grr = blockIdx.x * ROWS + rr;
      int gk = k0 + kk;
      sA[rr][kk] = (grr < n && gk < K) ? A[(size_t)grr * K + gk] : 0.0f;
    }
    for (int i = threadIdx.x; i < BK * FOUT; i += 256) {
      int kk = i / FOUT, f = i % FOUT;
      int gk = k0 + kk;
      sB[kk][f] = (gk < K) ? W[(size_t)gk * FOUT + f] : 0.0f;
    }
    __syncthreads();
#pragma unroll
    for (int kk = 0; kk < BK; ++kk) {
      float a = sA[r][kk];
#pragma unroll
      for (int j = 0; j < CPT; ++j) acc[j] += a * sB[kk][c0 + j];
    }
    __syncthreads();
  }

  if (gr < n) {
#pragma unroll
    for (int j = 0; j < CPT; ++j) out[(size_t)gr * FOUT + c0 + j] = acc[j] + bias[c0 + j];
  }
}

// ---------------- BatchNorm (training mode, biased var) + ReLU ----------------

__global__ __launch_bounds__(128) void bn_stats_kernel(const float* __restrict__ z,
                                                       float* __restrict__ sum,
                                                       float* __restrict__ sumsq, int n) {
  int f = threadIdx.x;  // 128 features
  float s = 0.0f, s2 = 0.0f;
  for (int r = blockIdx.x; r < n; r += gridDim.x) {
    float v = z[(size_t)r * FH + f];
    s += v;
    s2 += v * v;
  }
  unsafeAtomicAdd(&sum[f], s);
  unsafeAtomicAdd(&sumsq[f], s2);
}

__global__ __launch_bounds__(128) void bn_finalize_kernel(const float* __restrict__ sum,
                                                          const float* __restrict__ sumsq,
                                                          const float* __restrict__ g,
                                                          const float* __restrict__ be,
                                                          float* __restrict__ scale,
                                                          float* __restrict__ shift, int n) {
  int f = threadIdx.x;
  float invN = 1.0f / (float)n;
  float mean = sum[f] * invN;
  float var = sumsq[f] * invN - mean * mean;
  var = fmaxf(var, 0.0f);
  float sc = g[f] / sqrtf(var + BN_EPS);
  scale[f] = sc;
  shift[f] = be[f] - mean * sc;
}

__global__ __launch_bounds__(256) void bn_apply_relu_kernel(float* __restrict__ z,
                                                            const float* __restrict__ scale,
                                                            const float* __restrict__ shift,
                                                            int total4) {
  int i = blockIdx.x * blockDim.x + threadIdx.x;
  if (i >= total4) return;
  float4 v = reinterpret_cast<float4*>(z)[i];
  int f0 = (i * 4) & (FH - 1);
  v.x = fmaxf(v.x * scale[f0 + 0] + shift[f0 + 0], 0.0f);
  v.y = fmaxf(v.y * scale[f0 + 1] + shift[f0 + 1], 0.0f);
  v.z = fmaxf(v.z * scale[f0 + 2] + shift[f0 + 2], 0.0f);
  v.w = fmaxf(v.w * scale[f0 + 3] + shift[f0 + 3], 0.0f);
  reinterpret_cast<float4*>(z)[i] = v;
}

// ---------------- launch ----------------

extern "C" void kernel_launch(void* const* d_in, const int* in_sizes, int n_in,
                              void* d_out, int out_size, void* d_ws, size_t ws_size,
                              hipStream_t stream) {
  const float* x   = (const float*)d_in[0];
  const int*   ei  = (const int*)d_in[1];
  const float* ew  = (const float*)d_in[2];
  const float* W0  = (const float*)d_in[3];
  const float* b0  = (const float*)d_in[4];
  const float* g0  = (const float*)d_in[5];
  const float* be0 = (const float*)d_in[6];
  const float* W1  = (const float*)d_in[7];
  const float* b1  = (const float*)d_in[8];
  const float* g1  = (const float*)d_in[9];
  const float* be1 = (const float*)d_in[10];
  const float* W2  = (const float*)d_in[11];
  const float* b2  = (const float*)d_in[12];

  const int n = in_sizes[0] / F0;
  const int E = in_sizes[2];
  const int* row = ei;
  const int* col = ei + E;

  float* bufA  = (float*)d_ws;                       // n*FH floats (conv outputs)
  float* bufB  = bufA + (size_t)n * FH;              // n*FH floats (gemm outputs)
  float* coef  = bufB + (size_t)n * FH;              // E floats
  int*   deg   = (int*)(coef + E);                   // n ints
  float* dinv  = (float*)(deg + n);                  // n floats
  float* sum   = dinv + n;                           // 128
  float* sumsq = sum + FH;                           // 128
  float* scale = sumsq + FH;                         // 128
  float* shift = scale + FH;                         // 128

  const int total4 = n * FH / 4;
  const int gemm_blocks = ceil_div(n, 16);

  // --- degree / coefficients (shared by all 3 convs) ---
  hipMemsetAsync(deg, 0, (size_t)n * sizeof(int), stream);
  deg_count_kernel<<<ceil_div(E, 256), 256, 0, stream>>>(row, deg, E);
  dinv_kernel<<<ceil_div(n, 256), 256, 0, stream>>>(deg, dinv, n);
  coef_kernel<<<ceil_div(E, 256), 256, 0, stream>>>(row, col, ew, dinv, coef, E);

  // --- layer 0: conv(x,100) -> bufA; bufA@W0+b0 -> bufB; BN+ReLU in-place ---
  hipMemsetAsync(bufA, 0, (size_t)n * F0 * sizeof(float), stream);
  conv_atomic_kernel<F0><<<ceil_div((long long)E * (F0 / 4), 256), 256, 0, stream>>>(
      x, row, col, coef, bufA, E);
  gemm_bias_kernel<F0, FH, 16, 25><<<gemm_blocks, 256, 0, stream>>>(bufA, W0, b0, bufB, n);
  hipMemsetAsync(sum, 0, 2 * FH * sizeof(float), stream);
  bn_stats_kernel<<<256, 128, 0, stream>>>(bufB, sum, sumsq, n);
  bn_finalize_kernel<<<1, 128, 0, stream>>>(sum, sumsq, g0, be0, scale, shift, n);
  bn_apply_relu_kernel<<<ceil_div(total4, 256), 256, 0, stream>>>(bufB, scale, shift, total4);

  // --- layer 1: conv(bufB,128) -> bufA; bufA@W1+b1 -> bufB; BN+ReLU in-place ---
  hipMemsetAsync(bufA, 0, (size_t)n * FH * sizeof(float), stream);
  conv_atomic_kernel<FH><<<ceil_div((long long)E * (FH / 4), 256), 256, 0, stream>>>(
      bufB, row, col, coef, bufA, E);
  gemm_bias_kernel<FH, FH, 16, 32><<<gemm_blocks, 256, 0, stream>>>(bufA, W1, b1, bufB, n);
  hipMemsetAsync(sum, 0, 2 * FH * sizeof(float), stream);
  bn_stats_kernel<<<256, 128, 0, stream>>>(bufB, sum, sumsq, n);
  bn_finalize_kernel<<<1, 128, 0, stream>>>(sum, sumsq, g1, be1, scale, shift, n);
  bn_apply_relu_kernel<<<ceil_div(total4, 256), 256, 0, stream>>>(bufB, scale, shift, total4);

  // --- final: conv(bufB,128) -> bufA; bufA@W2+b2 -> d_out ---
  hipMemsetAsync(bufA, 0, (size_t)n * FH * sizeof(float), stream);
  conv_atomic_kernel<FH><<<ceil_div((long long)E * (FH / 4), 256), 256, 0, stream>>>(
      bufB, row, col, coef, bufA, E);
  gemm_bias_kernel<FH, FO, 16, 32><<<gemm_blocks, 256, 0, stream>>>(
      bufA, W2, b2, (float*)d_out, n);
}

// Round 3
// 1314.300 us; speedup vs baseline: 3.4381x; 3.4381x over previous
//
#include <hip/hip_runtime.h>
#include <cstdint>

#define F0 100
#define FH 128
#define FO 64
#define BN_EPS 1e-5f

static inline int ceil_div(long long a, long long b) { return (int)((a + b - 1) / b); }

// ---------------- histograms / normalization coefficients ----------------

__global__ __launch_bounds__(256) void hist2_kernel(const int* __restrict__ row,
                                                    const int* __restrict__ col,
                                                    int* __restrict__ degr,
                                                    int* __restrict__ degc, int E) {
  int e = blockIdx.x * blockDim.x + threadIdx.x;
  if (e < E) {
    atomicAdd(&degr[row[e]], 1);   // deg over sources (normalization, matches bincount(row))
    atomicAdd(&degc[col[e]], 1);   // deg over destinations (CSR bucketing)
  }
}

__global__ __launch_bounds__(256) void dinv_kernel(const int* __restrict__ degr,
                                                   float* __restrict__ dinv, int n) {
  int i = blockIdx.x * blockDim.x + threadIdx.x;
  if (i < n) {
    int d = degr[i];
    dinv[i] = (d > 0) ? rsqrtf((float)d) : 0.0f;
  }
}

// ---------------- exclusive scan of degc -> start (3-kernel scan) ----------------

__global__ __launch_bounds__(256) void scan_block_kernel(const int* __restrict__ in,
                                                         int* __restrict__ out,
                                                         int* __restrict__ bsums, int n) {
  __shared__ int s[256];
  int i = blockIdx.x * 256 + threadIdx.x;
  int v = (i < n) ? in[i] : 0;
  s[threadIdx.x] = v;
  __syncthreads();
  for (int off = 1; off < 256; off <<= 1) {
    int t = 0;
    if (threadIdx.x >= off) t = s[threadIdx.x - off];
    __syncthreads();
    if (threadIdx.x >= off) s[threadIdx.x] += t;
    __syncthreads();
  }
  if (i < n) out[i] = s[threadIdx.x] - v;  // exclusive
  if (threadIdx.x == 255) bsums[blockIdx.x] = s[255];
}

__global__ __launch_bounds__(256) void scan_partials_kernel(int* __restrict__ bsums, int nb) {
  __shared__ int s[256];
  int v = (threadIdx.x < nb) ? bsums[threadIdx.x] : 0;
  s[threadIdx.x] = v;
  __syncthreads();
  for (int off = 1; off < 256; off <<= 1) {
    int t = 0;
    if (threadIdx.x >= off) t = s[threadIdx.x - off];
    __syncthreads();
    if (threadIdx.x >= off) s[threadIdx.x] += t;
    __syncthreads();
  }
  if (threadIdx.x < nb) bsums[threadIdx.x] = s[threadIdx.x] - v;  // exclusive
}

__global__ __launch_bounds__(256) void scan_add_kernel(int* __restrict__ out,
                                                       const int* __restrict__ bsums, int n) {
  int i = blockIdx.x * 256 + threadIdx.x;
  if (i < n) out[i] += bsums[blockIdx.x];
}

// ---------------- CSR build: permute (src, coef) into dst-bucket order ----------------

__global__ __launch_bounds__(256) void csr_scatter_kernel(const int* __restrict__ row,
                                                          const int* __restrict__ col,
                                                          const float* __restrict__ ew,
                                                          const float* __restrict__ dinv,
                                                          const int* __restrict__ startA,
                                                          int* __restrict__ cursor,
                                                          int* __restrict__ srcp,
                                                          float* __restrict__ coefp, int E) {
  int e = blockIdx.x * blockDim.x + threadIdx.x;
  if (e >= E) return;
  int r = row[e], c = col[e];
  int pos = startA[c] + atomicAdd(&cursor[c], 1);
  srcp[pos] = r;
  coefp[pos] = dinv[r] * ew[e] * dinv[c];
}

// ---------------- graph conv as gather: out[dst,f] = bias[f] + sum coef*x[src,f] ----------------

template <int F>
__global__ __launch_bounds__(256) void conv_gather_kernel(const float* __restrict__ x,
                                                          const int* __restrict__ startA,
                                                          const int* __restrict__ degc,
                                                          const int* __restrict__ srcp,
                                                          const float* __restrict__ coefp,
                                                          const float* __restrict__ bias,
                                                          float* __restrict__ out, int n) {
  long long tid = (long long)blockIdx.x * 256 + threadIdx.x;
  if (tid >= (long long)n * F) return;
  int dst = (int)(tid / F);
  int f = (int)(tid % F);
  int s0 = startA[dst];
  int d = degc[dst];
  float acc = bias ? bias[f] : 0.0f;
  for (int k = 0; k < d; ++k) {
    int s = srcp[s0 + k];
    float c = coefp[s0 + k];
    acc = fmaf(c, x[(size_t)s * F + f], acc);
  }
  out[(size_t)dst * F + f] = acc;
}

// ---------------- GEMM: out[n x FOUT] = A[n x K] @ W[K x FOUT] (+ bias) ----------------

template <int K, int FOUT, int ROWS, int BK>
__global__ __launch_bounds__(256) void gemm_bias_kernel(const float* __restrict__ A,
                                                        const float* __restrict__ W,
                                                        const float* __restrict__ bias,
                                                        float* __restrict__ out, int n) {
  constexpr int TPR = 256 / ROWS;   // threads per row
  constexpr int CPT = FOUT / TPR;   // cols per thread (consecutive)
  __shared__ float sA[ROWS][BK];
  __shared__ float sB[BK][FOUT];

  int r = threadIdx.x / TPR;
  int c0 = (threadIdx.x % TPR) * CPT;
  int gr = blockIdx.x * ROWS + r;

  float acc[CPT];
#pragma unroll
  for (int j = 0; j < CPT; ++j) acc[j] = 0.0f;

  for (int k0 = 0; k0 < K; k0 += BK) {
    for (int i = threadIdx.x; i < ROWS * BK; i += 256) {
      int rr = i / BK, kk = i % BK;
      int grr = blockIdx.x * ROWS + rr;
      int gk = k0 + kk;
      sA[rr][kk] = (grr < n && gk < K) ? A[(size_t)grr * K + gk] : 0.0f;
    }
    for (int i = threadIdx.x; i < BK * FOUT; i += 256) {
      int kk = i / FOUT, f = i % FOUT;
      int gk = k0 + kk;
      sB[kk][f] = (gk < K) ? W[(size_t)gk * FOUT + f] : 0.0f;
    }
    __syncthreads();
#pragma unroll
    for (int kk = 0; kk < BK; ++kk) {
      float a = sA[r][kk];
#pragma unroll
      for (int j = 0; j < CPT; ++j) acc[j] += a * sB[kk][c0 + j];
    }
    __syncthreads();
  }

  if (gr < n) {
#pragma unroll
    for (int j = 0; j < CPT; ++j)
      out[(size_t)gr * FOUT + c0 + j] = acc[j] + (bias ? bias[c0 + j] : 0.0f);
  }
}

// ---------------- BatchNorm (training mode, biased var) + ReLU ----------------

__global__ __launch_bounds__(128) void bn_stats_kernel(const float* __restrict__ z,
                                                       float* __restrict__ sum,
                                                       float* __restrict__ sumsq, int n) {
  int f = threadIdx.x;  // 128 features
  float s = 0.0f, s2 = 0.0f;
  for (int r = blockIdx.x; r < n; r += gridDim.x) {
    float v = z[(size_t)r * FH + f];
    s += v;
    s2 += v * v;
  }
  unsafeAtomicAdd(&sum[f], s);
  unsafeAtomicAdd(&sumsq[f], s2);
}

__global__ __launch_bounds__(128) void bn_finalize_kernel(const float* __restrict__ sum,
                                                          const float* __restrict__ sumsq,
                                                          const float* __restrict__ g,
                                                          const float* __restrict__ be,
                                                          float* __restrict__ scale,
                                                          float* __restrict__ shift, int n) {
  int f = threadIdx.x;
  float invN = 1.0f / (float)n;
  float mean = sum[f] * invN;
  float var = sumsq[f] * invN - mean * mean;
  var = fmaxf(var, 0.0f);
  float sc = g[f] / sqrtf(var + BN_EPS);
  scale[f] = sc;
  shift[f] = be[f] - mean * sc;
}

__global__ __launch_bounds__(256) void bn_apply_relu_kernel(float* __restrict__ z,
                                                            const float* __restrict__ scale,
                                                            const float* __restrict__ shift,
                                                            int total4) {
  int i = blockIdx.x * blockDim.x + threadIdx.x;
  if (i >= total4) return;
  float4 v = reinterpret_cast<float4*>(z)[i];
  int f0 = (i * 4) & (FH - 1);
  v.x = fmaxf(v.x * scale[f0 + 0] + shift[f0 + 0], 0.0f);
  v.y = fmaxf(v.y * scale[f0 + 1] + shift[f0 + 1], 0.0f);
  v.z = fmaxf(v.z * scale[f0 + 2] + shift[f0 + 2], 0.0f);
  v.w = fmaxf(v.w * scale[f0 + 3] + shift[f0 + 3], 0.0f);
  reinterpret_cast<float4*>(z)[i] = v;
}

// ---------------- launch ----------------

extern "C" void kernel_launch(void* const* d_in, const int* in_sizes, int n_in,
                              void* d_out, int out_size, void* d_ws, size_t ws_size,
                              hipStream_t stream) {
  const float* x   = (const float*)d_in[0];
  const int*   ei  = (const int*)d_in[1];
  const float* ew  = (const float*)d_in[2];
  const float* W0  = (const float*)d_in[3];
  const float* b0  = (const float*)d_in[4];
  const float* g0  = (const float*)d_in[5];
  const float* be0 = (const float*)d_in[6];
  const float* W1  = (const float*)d_in[7];
  const float* b1  = (const float*)d_in[8];
  const float* g1  = (const float*)d_in[9];
  const float* be1 = (const float*)d_in[10];
  const float* W2  = (const float*)d_in[11];
  const float* b2  = (const float*)d_in[12];

  const int n = in_sizes[0] / F0;
  const int E = in_sizes[2];
  const int* row = ei;
  const int* col = ei + E;

  // workspace layout (no trailing backslashes in these comments!)
  float* bufA   = (float*)d_ws;                      // n*FH floats
  float* bufB   = bufA + (size_t)n * FH;             // n*FH floats
  int*   srcp   = (int*)(bufB + (size_t)n * FH);     // E ints
  float* coefp  = (float*)(srcp + E);                // E floats
  int*   degr   = (int*)(coefp + E);                 // n ints (zeroed with next two)
  int*   degc   = degr + n;                          // n ints
  int*   cursor = degc + n;                          // n ints
  int*   startA = cursor + n;                        // n ints
  float* dinv   = (float*)(startA + n);              // n floats
  int*   bsums  = (int*)(dinv + n);                  // 256 ints
  float* sum    = (float*)(bsums + 256);             // 128
  float* sumsq  = sum + FH;                          // 128
  float* scale  = sumsq + FH;                        // 128
  float* shift  = scale + FH;                        // 128

  const int total4 = n * FH / 4;
  const int gemm_blocks = ceil_div(n, 16);
  const int nb = ceil_div(n, 256);

  // --- CSR build (shared by all 3 convs) ---
  (void)hipMemsetAsync(degr, 0, 3 * (size_t)n * sizeof(int), stream);
  hist2_kernel<<<ceil_div(E, 256), 256, 0, stream>>>(row, col, degr, degc, E);
  dinv_kernel<<<ceil_div(n, 256), 256, 0, stream>>>(degr, dinv, n);
  scan_block_kernel<<<nb, 256, 0, stream>>>(degc, startA, bsums, n);
  scan_partials_kernel<<<1, 256, 0, stream>>>(bsums, nb);
  scan_add_kernel<<<nb, 256, 0, stream>>>(startA, bsums, n);
  csr_scatter_kernel<<<ceil_div(E, 256), 256, 0, stream>>>(row, col, ew, dinv, startA,
                                                           cursor, srcp, coefp, E);

  // --- layer 0: conv(x,100) -> bufA; bufA@W0+b0 -> bufB; BN+ReLU in-place ---
  conv_gather_kernel<F0><<<ceil_div((long long)n * F0, 256), 256, 0, stream>>>(
      x, startA, degc, srcp, coefp, nullptr, bufA, n);
  gemm_bias_kernel<F0, FH, 16, 25><<<gemm_blocks, 256, 0, stream>>>(bufA, W0, b0, bufB, n);
  (void)hipMemsetAsync(sum, 0, 2 * FH * sizeof(float), stream);
  bn_stats_kernel<<<256, 128, 0, stream>>>(bufB, sum, sumsq, n);
  bn_finalize_kernel<<<1, 128, 0, stream>>>(sum, sumsq, g0, be0, scale, shift, n);
  bn_apply_relu_kernel<<<ceil_div(total4, 256), 256, 0, stream>>>(bufB, scale, shift, total4);

  // --- layer 1: conv(bufB,128) -> bufA; bufA@W1+b1 -> bufB; BN+ReLU in-place ---
  conv_gather_kernel<FH><<<ceil_div((long long)n * FH, 256), 256, 0, stream>>>(
      bufB, startA, degc, srcp, coefp, nullptr, bufA, n);
  gemm_bias_kernel<FH, FH, 16, 32><<<gemm_blocks, 256, 0, stream>>>(bufA, W1, b1, bufB, n);
  (void)hipMemsetAsync(sum, 0, 2 * FH * sizeof(float), stream);
  bn_stats_kernel<<<256, 128, 0, stream>>>(bufB, sum, sumsq, n);
  bn_finalize_kernel<<<1, 128, 0, stream>>>(sum, sumsq, g1, be1, scale, shift, n);
  bn_apply_relu_kernel<<<ceil_div(total4, 256), 256, 0, stream>>>(bufB, scale, shift, total4);

  // --- final layer, commuted: (bufB @ W2) -> bufA[n x 64]; conv+bias -> d_out ---
  // conv is linear over the node dim, so conv(x) @ W2 + b2 == conv(x @ W2) + b2.
  gemm_bias_kernel<FH, FO, 16, 32><<<gemm_blocks, 256, 0, stream>>>(bufB, W2, nullptr, bufA, n);
  conv_gather_kernel<FO><<<ceil_div((long long)n * FO, 256), 256, 0, stream>>>(
      bufA, startA, degc, srcp, coefp, b2, (float*)d_out, n);
}

// Round 4
// 498.615 us; speedup vs baseline: 9.0624x; 2.6359x over previous
//
#include <hip/hip_runtime.h>
#include <cstdint>

#define F0 100
#define FH 128
#define FO 64
#define BN_EPS 1e-5f

static inline int ceil_div(long long a, long long b) { return (int)((a + b - 1) / b); }

// ---------------- histograms / normalization coefficients ----------------

__global__ __launch_bounds__(256) void hist2_kernel(const int* __restrict__ row,
                                                    const int* __restrict__ col,
                                                    int* __restrict__ degr,
                                                    int* __restrict__ degc, int E) {
  int e = blockIdx.x * blockDim.x + threadIdx.x;
  if (e < E) {
    atomicAdd(&degr[row[e]], 1);
    atomicAdd(&degc[col[e]], 1);
  }
}

__global__ __launch_bounds__(256) void dinv_kernel(const int* __restrict__ degr,
                                                   float* __restrict__ dinv, int n) {
  int i = blockIdx.x * blockDim.x + threadIdx.x;
  if (i < n) {
    int d = degr[i];
    dinv[i] = (d > 0) ? rsqrtf((float)d) : 0.0f;
  }
}

// ---------------- exclusive scan of degc -> startA ----------------

__global__ __launch_bounds__(256) void scan_block_kernel(const int* __restrict__ in,
                                                         int* __restrict__ out,
                                                         int* __restrict__ bsums, int n) {
  __shared__ int s[256];
  int i = blockIdx.x * 256 + threadIdx.x;
  int v = (i < n) ? in[i] : 0;
  s[threadIdx.x] = v;
  __syncthreads();
  for (int off = 1; off < 256; off <<= 1) {
    int t = 0;
    if (threadIdx.x >= off) t = s[threadIdx.x - off];
    __syncthreads();
    if (threadIdx.x >= off) s[threadIdx.x] += t;
    __syncthreads();
  }
  if (i < n) out[i] = s[threadIdx.x] - v;
  if (threadIdx.x == 255) bsums[blockIdx.x] = s[255];
}

__global__ __launch_bounds__(256) void scan_partials_kernel(int* __restrict__ bsums, int nb) {
  __shared__ int s[256];
  int v = (threadIdx.x < nb) ? bsums[threadIdx.x] : 0;
  s[threadIdx.x] = v;
  __syncthreads();
  for (int off = 1; off < 256; off <<= 1) {
    int t = 0;
    if (threadIdx.x >= off) t = s[threadIdx.x - off];
    __syncthreads();
    if (threadIdx.x >= off) s[threadIdx.x] += t;
    __syncthreads();
  }
  if (threadIdx.x < nb) bsums[threadIdx.x] = s[threadIdx.x] - v;
}

__global__ __launch_bounds__(256) void scan_add_kernel(int* __restrict__ out,
                                                       const int* __restrict__ bsums, int n) {
  int i = blockIdx.x * 256 + threadIdx.x;
  if (i < n) out[i] += bsums[blockIdx.x];
}

// ---------------- CSR build: packed (src, coef) per edge, dst-bucket order ----------------

__global__ __launch_bounds__(256) void csr_scatter_kernel(const int* __restrict__ row,
                                                          const int* __restrict__ col,
                                                          const float* __restrict__ ew,
                                                          const float* __restrict__ dinv,
                                                          const int* __restrict__ startA,
                                                          int* __restrict__ cursor,
                                                          int2* __restrict__ ep, int E) {
  int e = blockIdx.x * blockDim.x + threadIdx.x;
  if (e >= E) return;
  int r = row[e], c = col[e];
  int pos = startA[c] + atomicAdd(&cursor[c], 1);
  float coef = dinv[r] * ew[e] * dinv[c];
  ep[pos] = make_int2(r, __float_as_int(coef));
}

// ---------------- conv gather (float4): out[dst, 4g] = bias + sum coef * x[src, 4g] ----------------

template <int F>
__global__ __launch_bounds__(256) void conv_gather_kernel(const float* __restrict__ x,
                                                          const int* __restrict__ startA,
                                                          const int* __restrict__ degc,
                                                          const int2* __restrict__ ep,
                                                          const float* __restrict__ bias,
                                                          float* __restrict__ out, int n) {
  constexpr int G = F / 4;
  long long tid = (long long)blockIdx.x * 256 + threadIdx.x;
  if (tid >= (long long)n * G) return;
  int dst = (int)(tid / G);
  int g = (int)(tid % G);
  int s0 = startA[dst];
  int d = degc[dst];
  const float4* x4 = (const float4*)x;
  float4 acc = make_float4(0.f, 0.f, 0.f, 0.f);
  for (int k = 0; k < d; ++k) {
    int2 e = ep[s0 + k];
    float c = __int_as_float(e.y);
    float4 xv = x4[(size_t)e.x * G + g];
    acc.x = fmaf(c, xv.x, acc.x);
    acc.y = fmaf(c, xv.y, acc.y);
    acc.z = fmaf(c, xv.z, acc.z);
    acc.w = fmaf(c, xv.w, acc.w);
  }
  if (bias) {
    float4 bb = ((const float4*)bias)[g];
    acc.x += bb.x; acc.y += bb.y; acc.z += bb.z; acc.w += bb.w;
  }
  ((float4*)out)[(size_t)dst * G + g] = acc;
}

// ---------------- GEMM: out[n x F] = A[n x K] @ W[K x F] (+ bias) ----------------
// 256 threads, tile BR=NRG*TM rows x F cols. Thread = (row-group, 4-col group),
// acc = TM x float4 (<=32 VGPR). sA reads are wave-broadcast (2 addrs/wave), sW
// reads contiguous float4. K assumed %4==0 (100, 128).

template <int K, int F, int TM>
__global__ __launch_bounds__(256) void gemm2_kernel(const float* __restrict__ A,
                                                    const float* __restrict__ W,
                                                    const float* __restrict__ bias,
                                                    float* __restrict__ out, int n) {
  constexpr int NCG = F / 4;        // col groups
  constexpr int NRG = 256 / NCG;    // row groups
  constexpr int BR = NRG * TM;      // rows per block
  constexpr int BK = 32;
  constexpr int K4 = K / 4;
  constexpr int F4 = F / 4;

  __shared__ float sW[BK][F];
  __shared__ float sA[BR][BK];

  const int tid = threadIdx.x;
  const int cg = tid % NCG;
  const int rg = tid / NCG;
  const int row0 = blockIdx.x * BR;

  float4 acc[TM];
#pragma unroll
  for (int t = 0; t < TM; ++t) acc[t] = make_float4(0.f, 0.f, 0.f, 0.f);

  const float4* A4 = (const float4*)A;
  const float4* W4 = (const float4*)W;
  const float4 z4 = make_float4(0.f, 0.f, 0.f, 0.f);

  for (int k0 = 0; k0 < K; k0 += BK) {
    // stage W chunk [BK x F]
    for (int i = tid; i < BK * F4; i += 256) {
      int kk = i / F4, f4 = i % F4;
      int gk = k0 + kk;
      ((float4*)&sW[kk][0])[f4] = (gk < K) ? W4[(size_t)gk * F4 + f4] : z4;
    }
    // stage A chunk [BR x BK]
    for (int i = tid; i < BR * (BK / 4); i += 256) {
      int r = i / (BK / 4), k4 = i % (BK / 4);
      int gr = row0 + r;
      int gk = k0 + k4 * 4;
      ((float4*)&sA[r][0])[k4] =
          (gr < n && gk + 3 < K) ? A4[(size_t)gr * K4 + (gk >> 2)] : z4;
    }
    __syncthreads();
#pragma unroll 4
    for (int kk = 0; kk < BK; ++kk) {
      float4 w = ((const float4*)&sW[kk][0])[cg];
#pragma unroll
      for (int t = 0; t < TM; ++t) {
        float a = sA[rg * TM + t][kk];
        acc[t].x = fmaf(a, w.x, acc[t].x);
        acc[t].y = fmaf(a, w.y, acc[t].y);
        acc[t].z = fmaf(a, w.z, acc[t].z);
        acc[t].w = fmaf(a, w.w, acc[t].w);
      }
    }
    __syncthreads();
  }

  float4 bb = bias ? ((const float4*)bias)[cg] : z4;
#pragma unroll
  for (int t = 0; t < TM; ++t) {
    int gr = row0 + rg * TM + t;
    if (gr < n) {
      float4 v = acc[t];
      v.x += bb.x; v.y += bb.y; v.z += bb.z; v.w += bb.w;
      ((float4*)out)[(size_t)gr * F4 + cg] = v;
    }
  }
}

// ---------------- BatchNorm (training mode, biased var) + ReLU ----------------

__global__ __launch_bounds__(128) void bn_stats_kernel(const float* __restrict__ z,
                                                       float* __restrict__ sum,
                                                       float* __restrict__ sumsq, int n) {
  int f = threadIdx.x;
  float s = 0.0f, s2 = 0.0f;
  for (int r = blockIdx.x; r < n; r += gridDim.x) {
    float v = z[(size_t)r * FH + f];
    s += v;
    s2 += v * v;
  }
  unsafeAtomicAdd(&sum[f], s);
  unsafeAtomicAdd(&sumsq[f], s2);
}

__global__ __launch_bounds__(128) void bn_finalize_kernel(const float* __restrict__ sum,
                                                          const float* __restrict__ sumsq,
                                                          const float* __restrict__ g,
                                                          const float* __restrict__ be,
                                                          float* __restrict__ scale,
                                                          float* __restrict__ shift, int n) {
  int f = threadIdx.x;
  float invN = 1.0f / (float)n;
  float mean = sum[f] * invN;
  float var = sumsq[f] * invN - mean * mean;
  var = fmaxf(var, 0.0f);
  float sc = g[f] / sqrtf(var + BN_EPS);
  scale[f] = sc;
  shift[f] = be[f] - mean * sc;
}

__global__ __launch_bounds__(256) void bn_apply_relu_kernel(float* __restrict__ z,
                                                            const float* __restrict__ scale,
                                                            const float* __restrict__ shift,
                                                            int total4) {
  int i = blockIdx.x * blockDim.x + threadIdx.x;
  if (i >= total4) return;
  float4 v = reinterpret_cast<float4*>(z)[i];
  int f0 = (i * 4) & (FH - 1);
  v.x = fmaxf(v.x * scale[f0 + 0] + shift[f0 + 0], 0.0f);
  v.y = fmaxf(v.y * scale[f0 + 1] + shift[f0 + 1], 0.0f);
  v.z = fmaxf(v.z * scale[f0 + 2] + shift[f0 + 2], 0.0f);
  v.w = fmaxf(v.w * scale[f0 + 3] + shift[f0 + 3], 0.0f);
  reinterpret_cast<float4*>(z)[i] = v;
}

// ---------------- launch ----------------

extern "C" void kernel_launch(void* const* d_in, const int* in_sizes, int n_in,
                              void* d_out, int out_size, void* d_ws, size_t ws_size,
                              hipStream_t stream) {
  const float* x   = (const float*)d_in[0];
  const int*   ei  = (const int*)d_in[1];
  const float* ew  = (const float*)d_in[2];
  const float* W0  = (const float*)d_in[3];
  const float* b0  = (const float*)d_in[4];
  const float* g0  = (const float*)d_in[5];
  const float* be0 = (const float*)d_in[6];
  const float* W1  = (const float*)d_in[7];
  const float* b1  = (const float*)d_in[8];
  const float* g1  = (const float*)d_in[9];
  const float* be1 = (const float*)d_in[10];
  const float* W2  = (const float*)d_in[11];
  const float* b2  = (const float*)d_in[12];

  const int n = in_sizes[0] / F0;
  const int E = in_sizes[2];
  const int* row = ei;
  const int* col = ei + E;

  // workspace layout
  float* bufA   = (float*)d_ws;                      // n*FH floats
  float* bufB   = bufA + (size_t)n * FH;             // n*FH floats
  int2*  ep     = (int2*)(bufB + (size_t)n * FH);    // E int2 (packed src,coef)
  int*   degr   = (int*)(ep + E);                    // n ints (zeroed with next two)
  int*   degc   = degr + n;                          // n ints
  int*   cursor = degc + n;                          // n ints
  int*   startA = cursor + n;                        // n ints
  float* dinv   = (float*)(startA + n);              // n floats
  int*   bsums  = (int*)(dinv + n);                  // 256 ints
  float* sum    = (float*)(bsums + 256);             // 128
  float* sumsq  = sum + FH;                          // 128
  float* scale  = sumsq + FH;                        // 128
  float* shift  = scale + FH;                        // 128

  const int total4 = n * FH / 4;
  const int nb = ceil_div(n, 256);
  const int gemm_blocks = ceil_div(n, 64);  // BR=64 for all three instantiations

  // --- CSR build (shared by all 3 convs) ---
  (void)hipMemsetAsync(degr, 0, 3 * (size_t)n * sizeof(int), stream);
  hist2_kernel<<<ceil_div(E, 256), 256, 0, stream>>>(row, col, degr, degc, E);
  dinv_kernel<<<ceil_div(n, 256), 256, 0, stream>>>(degr, dinv, n);
  scan_block_kernel<<<nb, 256, 0, stream>>>(degc, startA, bsums, n);
  scan_partials_kernel<<<1, 256, 0, stream>>>(bsums, nb);
  scan_add_kernel<<<nb, 256, 0, stream>>>(startA, bsums, n);
  csr_scatter_kernel<<<ceil_div(E, 256), 256, 0, stream>>>(row, col, ew, dinv, startA,
                                                           cursor, ep, E);

  // --- layer 0 ---
  conv_gather_kernel<F0><<<ceil_div((long long)n * (F0 / 4), 256), 256, 0, stream>>>(
      x, startA, degc, ep, nullptr, bufA, n);
  gemm2_kernel<F0, FH, 8><<<gemm_blocks, 256, 0, stream>>>(bufA, W0, b0, bufB, n);
  (void)hipMemsetAsync(sum, 0, 2 * FH * sizeof(float), stream);
  bn_stats_kernel<<<256, 128, 0, stream>>>(bufB, sum, sumsq, n);
  bn_finalize_kernel<<<1, 128, 0, stream>>>(sum, sumsq, g0, be0, scale, shift, n);
  bn_apply_relu_kernel<<<ceil_div(total4, 256), 256, 0, stream>>>(bufB, scale, shift, total4);

  // --- layer 1 ---
  conv_gather_kernel<FH><<<ceil_div((long long)n * (FH / 4), 256), 256, 0, stream>>>(
      bufB, startA, degc, ep, nullptr, bufA, n);
  gemm2_kernel<FH, FH, 8><<<gemm_blocks, 256, 0, stream>>>(bufA, W1, b1, bufB, n);
  (void)hipMemsetAsync(sum, 0, 2 * FH * sizeof(float), stream);
  bn_stats_kernel<<<256, 128, 0, stream>>>(bufB, sum, sumsq, n);
  bn_finalize_kernel<<<1, 128, 0, stream>>>(sum, sumsq, g1, be1, scale, shift, n);
  bn_apply_relu_kernel<<<ceil_div(total4, 256), 256, 0, stream>>>(bufB, scale, shift, total4);

  // --- final layer, commuted: (bufB @ W2) -> bufA[n x 64]; conv+bias -> d_out ---
  gemm2_kernel<FH, FO, 4><<<gemm_blocks, 256, 0, stream>>>(bufB, W2, nullptr, bufA, n);
  conv_gather_kernel<FO><<<ceil_div((long long)n * (FO / 4), 256), 256, 0, stream>>>(
      bufA, startA, degc, ep, b2, (float*)d_out, n);
}

// Round 5
// 488.968 us; speedup vs baseline: 9.2412x; 1.0197x over previous
//
#include <hip/hip_runtime.h>
#include <cstdint>

#define F0 100
#define FH 128
#define FO 64
#define NCPY 8
#define BN_EPS 1e-5f

static inline int ceil_div(long long a, long long b) { return (int)((a + b - 1) / b); }

// XCD id (0..7 on MI355X). hwreg(20,0,32) = HW_REG_XCC_ID on gfx94x/gfx950.
// Any value works for correctness (masked to copy range); XCD-accurate values
// keep each histogram copy's lines exclusive to one XCD's L2.
__device__ __forceinline__ int xcc_copy() {
  int v;
  asm volatile("s_getreg_b32 %0, hwreg(20, 0, 32)" : "=s"(v));
  return v & (NCPY - 1);
}

// ---- pass 1: multi-copy histograms + per-edge rank within (copy, dst) bucket ----

__global__ __launch_bounds__(256) void hist_pos_kernel(const int* __restrict__ row,
                                                       const int* __restrict__ col,
                                                       int* __restrict__ degr_cp,
                                                       int* __restrict__ degc_cp,
                                                       int* __restrict__ posw, int E, int n) {
  int e = blockIdx.x * blockDim.x + threadIdx.x;
  if (e >= E) return;
  int j = xcc_copy();
  int r = row[e], c = col[e];
  atomicAdd(&degr_cp[(size_t)j * n + r], 1);
  int pos = atomicAdd(&degc_cp[(size_t)j * n + c], 1);
  posw[e] = pos | (j << 28);  // rank in copy-j bucket of node c
}

// ---- reduce copies -> degc, dinv ----

__global__ __launch_bounds__(256) void reduce_deg_kernel(const int* __restrict__ degr_cp,
                                                         const int* __restrict__ degc_cp,
                                                         int* __restrict__ degc,
                                                         float* __restrict__ dinv, int n) {
  int i = blockIdx.x * blockDim.x + threadIdx.x;
  if (i >= n) return;
  int dr = 0, dc = 0;
#pragma unroll
  for (int j = 0; j < NCPY; ++j) {
    dr += degr_cp[(size_t)j * n + i];
    dc += degc_cp[(size_t)j * n + i];
  }
  degc[i] = dc;
  dinv[i] = (dr > 0) ? rsqrtf((float)dr) : 0.0f;
}

// ---- exclusive scan of degc -> startA ----

__global__ __launch_bounds__(256) void scan_block_kernel(const int* __restrict__ in,
                                                         int* __restrict__ out,
                                                         int* __restrict__ bsums, int n) {
  __shared__ int s[256];
  int i = blockIdx.x * 256 + threadIdx.x;
  int v = (i < n) ? in[i] : 0;
  s[threadIdx.x] = v;
  __syncthreads();
  for (int off = 1; off < 256; off <<= 1) {
    int t = 0;
    if (threadIdx.x >= off) t = s[threadIdx.x - off];
    __syncthreads();
    if (threadIdx.x >= off) s[threadIdx.x] += t;
    __syncthreads();
  }
  if (i < n) out[i] = s[threadIdx.x] - v;
  if (threadIdx.x == 255) bsums[blockIdx.x] = s[255];
}

__global__ __launch_bounds__(256) void scan_partials_kernel(int* __restrict__ bsums, int nb) {
  __shared__ int s[256];
  int v = (threadIdx.x < nb) ? bsums[threadIdx.x] : 0;
  s[threadIdx.x] = v;
  __syncthreads();
  for (int off = 1; off < 256; off <<= 1) {
    int t = 0;
    if (threadIdx.x >= off) t = s[threadIdx.x - off];
    __syncthreads();
    if (threadIdx.x >= off) s[threadIdx.x] += t;
    __syncthreads();
  }
  if (threadIdx.x < nb) bsums[threadIdx.x] = s[threadIdx.x] - v;
}

__global__ __launch_bounds__(256) void scan_add_kernel(int* __restrict__ out,
                                                       const int* __restrict__ bsums, int n) {
  int i = blockIdx.x * 256 + threadIdx.x;
  if (i < n) out[i] += bsums[blockIdx.x];
}

// ---- per-(copy,node) base offsets: copyOff[j][c] = startA[c] + sum_{i<j} degc_cp[i][c] ----

__global__ __launch_bounds__(256) void copyoff_kernel(const int* __restrict__ startA,
                                                      const int* __restrict__ degc_cp,
                                                      int* __restrict__ copyOff, int n) {
  int c = blockIdx.x * blockDim.x + threadIdx.x;
  if (c >= n) return;
  int running = startA[c];
#pragma unroll
  for (int j = 0; j < NCPY; ++j) {
    copyOff[(size_t)j * n + c] = running;
    running += degc_cp[(size_t)j * n + c];
  }
}

// ---- pass 2: atomic-free scatter of packed (src, coef) into dst-bucket order ----

__global__ __launch_bounds__(256) void csr_scatter2_kernel(const int* __restrict__ row,
                                                           const int* __restrict__ col,
                                                           const float* __restrict__ ew,
                                                           const float* __restrict__ dinv,
                                                           const int* __restrict__ copyOff,
                                                           const int* __restrict__ posw,
                                                           int2* __restrict__ ep, int E, int n) {
  int e = blockIdx.x * blockDim.x + threadIdx.x;
  if (e >= E) return;
  int r = row[e], c = col[e];
  int pw = posw[e];
  int j = pw >> 28;
  int pos = copyOff[(size_t)j * n + c] + (pw & 0x0FFFFFFF);
  float coef = dinv[r] * ew[e] * dinv[c];
  ep[pos] = make_int2(r, __float_as_int(coef));
}

// ---- conv gather, 4 float4s per thread: out[dst] = bias + sum coef * x[src] ----

template <int F>
__global__ __launch_bounds__(256) void conv_gather4_kernel(const float* __restrict__ x,
                                                           const int* __restrict__ startA,
                                                           const int* __restrict__ degc,
                                                           const int2* __restrict__ ep,
                                                           const float* __restrict__ bias,
                                                           float* __restrict__ out, int n) {
  constexpr int G = F / 4;    // float4 groups per row
  constexpr int TPD = G / 4;  // threads per dst (4 float4 each)
  long long tid = (long long)blockIdx.x * 256 + threadIdx.x;
  if (tid >= (long long)n * TPD) return;
  int dst = (int)(tid / TPD);
  int q = (int)(tid % TPD);
  int s0 = startA[dst];
  int d = degc[dst];
  const float4* x4 = (const float4*)x;
  float4 a0 = make_float4(0.f, 0.f, 0.f, 0.f), a1 = a0, a2 = a0, a3 = a0;
  for (int k = 0; k < d; ++k) {
    int2 e = ep[s0 + k];
    float c = __int_as_float(e.y);
    const float4* xp = x4 + (size_t)e.x * G + q;
    float4 v0 = xp[0], v1 = xp[TPD], v2 = xp[2 * TPD], v3 = xp[3 * TPD];
    a0.x = fmaf(c, v0.x, a0.x); a0.y = fmaf(c, v0.y, a0.y);
    a0.z = fmaf(c, v0.z, a0.z); a0.w = fmaf(c, v0.w, a0.w);
    a1.x = fmaf(c, v1.x, a1.x); a1.y = fmaf(c, v1.y, a1.y);
    a1.z = fmaf(c, v1.z, a1.z); a1.w = fmaf(c, v1.w, a1.w);
    a2.x = fmaf(c, v2.x, a2.x); a2.y = fmaf(c, v2.y, a2.y);
    a2.z = fmaf(c, v2.z, a2.z); a2.w = fmaf(c, v2.w, a2.w);
    a3.x = fmaf(c, v3.x, a3.x); a3.y = fmaf(c, v3.y, a3.y);
    a3.z = fmaf(c, v3.z, a3.z); a3.w = fmaf(c, v3.w, a3.w);
  }
  float4* o4 = (float4*)out + (size_t)dst * G + q;
  if (bias) {
    const float4* b4 = (const float4*)bias + q;
    float4 b0v = b4[0], b1v = b4[TPD], b2v = b4[2 * TPD], b3v = b4[3 * TPD];
    a0.x += b0v.x; a0.y += b0v.y; a0.z += b0v.z; a0.w += b0v.w;
    a1.x += b1v.x; a1.y += b1v.y; a1.z += b1v.z; a1.w += b1v.w;
    a2.x += b2v.x; a2.y += b2v.y; a2.z += b2v.z; a2.w += b2v.w;
    a3.x += b3v.x; a3.y += b3v.y; a3.z += b3v.z; a3.w += b3v.w;
  }
  o4[0] = a0; o4[TPD] = a1; o4[2 * TPD] = a2; o4[3 * TPD] = a3;
}

// ---- GEMM: out[n x F] = A[n x K] @ W[K x F] (+ bias) ----

template <int K, int F, int TM>
__global__ __launch_bounds__(256) void gemm2_kernel(const float* __restrict__ A,
                                                    const float* __restrict__ W,
                                                    const float* __restrict__ bias,
                                                    float* __restrict__ out, int n) {
  constexpr int NCG = F / 4;
  constexpr int NRG = 256 / NCG;
  constexpr int BR = NRG * TM;
  constexpr int BK = 32;
  constexpr int K4 = K / 4;
  constexpr int F4 = F / 4;

  __shared__ float sW[BK][F];
  __shared__ float sA[BR][BK];

  const int tid = threadIdx.x;
  const int cg = tid % NCG;
  const int rg = tid / NCG;
  const int row0 = blockIdx.x * BR;

  float4 acc[TM];
#pragma unroll
  for (int t = 0; t < TM; ++t) acc[t] = make_float4(0.f, 0.f, 0.f, 0.f);

  const float4* A4 = (const float4*)A;
  const float4* W4 = (const float4*)W;
  const float4 z4 = make_float4(0.f, 0.f, 0.f, 0.f);

  for (int k0 = 0; k0 < K; k0 += BK) {
    for (int i = tid; i < BK * F4; i += 256) {
      int kk = i / F4, f4 = i % F4;
      int gk = k0 + kk;
      ((float4*)&sW[kk][0])[f4] = (gk < K) ? W4[(size_t)gk * F4 + f4] : z4;
    }
    for (int i = tid; i < BR * (BK / 4); i += 256) {
      int r = i / (BK / 4), k4 = i % (BK / 4);
      int gr = row0 + r;
      int gk = k0 + k4 * 4;
      ((float4*)&sA[r][0])[k4] =
          (gr < n && gk + 3 < K) ? A4[(size_t)gr * K4 + (gk >> 2)] : z4;
    }
    __syncthreads();
#pragma unroll 4
    for (int kk = 0; kk < BK; ++kk) {
      float4 w = ((const float4*)&sW[kk][0])[cg];
#pragma unroll
      for (int t = 0; t < TM; ++t) {
        float a = sA[rg * TM + t][kk];
        acc[t].x = fmaf(a, w.x, acc[t].x);
        acc[t].y = fmaf(a, w.y, acc[t].y);
        acc[t].z = fmaf(a, w.z, acc[t].z);
        acc[t].w = fmaf(a, w.w, acc[t].w);
      }
    }
    __syncthreads();
  }

  float4 bb = bias ? ((const float4*)bias)[cg] : z4;
#pragma unroll
  for (int t = 0; t < TM; ++t) {
    int gr = row0 + rg * TM + t;
    if (gr < n) {
      float4 v = acc[t];
      v.x += bb.x; v.y += bb.y; v.z += bb.z; v.w += bb.w;
      ((float4*)out)[(size_t)gr * F4 + cg] = v;
    }
  }
}

// ---- BatchNorm (training mode, biased var) + ReLU ----

__global__ __launch_bounds__(128) void bn_stats_kernel(const float* __restrict__ z,
                                                       float* __restrict__ sum,
                                                       float* __restrict__ sumsq, int n) {
  int f = threadIdx.x;
  float s = 0.0f, s2 = 0.0f;
  for (int r = blockIdx.x; r < n; r += gridDim.x) {
    float v = z[(size_t)r * FH + f];
    s += v;
    s2 += v * v;
  }
  unsafeAtomicAdd(&sum[f], s);
  unsafeAtomicAdd(&sumsq[f], s2);
}

__global__ __launch_bounds__(128) void bn_finalize_kernel(const float* __restrict__ sum,
                                                          const float* __restrict__ sumsq,
                                                          const float* __restrict__ g,
                                                          const float* __restrict__ be,
                                                          float* __restrict__ scale,
                                                          float* __restrict__ shift, int n) {
  int f = threadIdx.x;
  float invN = 1.0f / (float)n;
  float mean = sum[f] * invN;
  float var = sumsq[f] * invN - mean * mean;
  var = fmaxf(var, 0.0f);
  float sc = g[f] / sqrtf(var + BN_EPS);
  scale[f] = sc;
  shift[f] = be[f] - mean * sc;
}

__global__ __launch_bounds__(256) void bn_apply_relu_kernel(float* __restrict__ z,
                                                            const float* __restrict__ scale,
                                                            const float* __restrict__ shift,
                                                            int total4) {
  int i = blockIdx.x * blockDim.x + threadIdx.x;
  if (i >= total4) return;
  float4 v = reinterpret_cast<float4*>(z)[i];
  int f0 = (i * 4) & (FH - 1);
  v.x = fmaxf(v.x * scale[f0 + 0] + shift[f0 + 0], 0.0f);
  v.y = fmaxf(v.y * scale[f0 + 1] + shift[f0 + 1], 0.0f);
  v.z = fmaxf(v.z * scale[f0 + 2] + shift[f0 + 2], 0.0f);
  v.w = fmaxf(v.w * scale[f0 + 3] + shift[f0 + 3], 0.0f);
  reinterpret_cast<float4*>(z)[i] = v;
}

// ---- launch ----

extern "C" void kernel_launch(void* const* d_in, const int* in_sizes, int n_in,
                              void* d_out, int out_size, void* d_ws, size_t ws_size,
                              hipStream_t stream) {
  const float* x   = (const float*)d_in[0];
  const int*   ei  = (const int*)d_in[1];
  const float* ew  = (const float*)d_in[2];
  const float* W0  = (const float*)d_in[3];
  const float* b0  = (const float*)d_in[4];
  const float* g0  = (const float*)d_in[5];
  const float* be0 = (const float*)d_in[6];
  const float* W1  = (const float*)d_in[7];
  const float* b1  = (const float*)d_in[8];
  const float* g1  = (const float*)d_in[9];
  const float* be1 = (const float*)d_in[10];
  const float* W2  = (const float*)d_in[11];
  const float* b2  = (const float*)d_in[12];

  const int n = in_sizes[0] / F0;
  const int E = in_sizes[2];
  const int* row = ei;
  const int* col = ei + E;

  // persistent workspace
  float* bufA   = (float*)d_ws;                      // n*FH floats
  float* bufB   = bufA + (size_t)n * FH;             // n*FH floats
  int2*  ep     = (int2*)(bufB + (size_t)n * FH);    // E int2
  int*   degc   = (int*)(ep + E);                    // n ints
  int*   startA = degc + n;                          // n ints
  float* dinv   = (float*)(startA + n);              // n floats
  int*   bsums  = (int*)(dinv + n);                  // 256 ints
  float* sum    = (float*)(bsums + 256);             // 128
  float* sumsq  = sum + FH;                          // 128
  float* scale  = sumsq + FH;                        // 128
  float* shift  = scale + FH;                        // 128
  // CSR-build transients aliased into bufA (bufA first written after CSR build)
  int*   posw    = (int*)bufA;                       // E ints
  int*   degr_cp = posw + E;                         // NCPY*n ints (zeroed with degc_cp)
  int*   degc_cp = degr_cp + (size_t)NCPY * n;       // NCPY*n ints
  int*   copyOff = degc_cp + (size_t)NCPY * n;       // NCPY*n ints

  const int total4 = n * FH / 4;
  const int nb = ceil_div(n, 256);
  const int gemm_blocks = ceil_div(n, 64);

  // --- CSR build (shared by all 3 convs) ---
  (void)hipMemsetAsync(degr_cp, 0, 2 * (size_t)NCPY * n * sizeof(int), stream);
  hist_pos_kernel<<<ceil_div(E, 256), 256, 0, stream>>>(row, col, degr_cp, degc_cp, posw, E, n);
  reduce_deg_kernel<<<nb, 256, 0, stream>>>(degr_cp, degc_cp, degc, dinv, n);
  scan_block_kernel<<<nb, 256, 0, stream>>>(degc, startA, bsums, n);
  scan_partials_kernel<<<1, 256, 0, stream>>>(bsums, nb);
  scan_add_kernel<<<nb, 256, 0, stream>>>(startA, bsums, n);
  copyoff_kernel<<<nb, 256, 0, stream>>>(startA, degc_cp, copyOff, n);
  csr_scatter2_kernel<<<ceil_div(E, 256), 256, 0, stream>>>(row, col, ew, dinv, copyOff,
                                                            posw, ep, E, n);

  // --- layer 0, commuted: t = x@W0 -> bufA; conv(t)+b0 -> bufB; BN+ReLU in place ---
  gemm2_kernel<F0, FH, 8><<<gemm_blocks, 256, 0, stream>>>(x, W0, nullptr, bufA, n);
  conv_gather4_kernel<FH><<<ceil_div((long long)n * (FH / 16), 256), 256, 0, stream>>>(
      bufA, startA, degc, ep, b0, bufB, n);
  (void)hipMemsetAsync(sum, 0, 2 * FH * sizeof(float), stream);
  bn_stats_kernel<<<256, 128, 0, stream>>>(bufB, sum, sumsq, n);
  bn_finalize_kernel<<<1, 128, 0, stream>>>(sum, sumsq, g0, be0, scale, shift, n);
  bn_apply_relu_kernel<<<ceil_div(total4, 256), 256, 0, stream>>>(bufB, scale, shift, total4);

  // --- layer 1: conv(bufB) -> bufA; bufA@W1+b1 -> bufB; BN+ReLU in place ---
  conv_gather4_kernel<FH><<<ceil_div((long long)n * (FH / 16), 256), 256, 0, stream>>>(
      bufB, startA, degc, ep, nullptr, bufA, n);
  gemm2_kernel<FH, FH, 8><<<gemm_blocks, 256, 0, stream>>>(bufA, W1, b1, bufB, n);
  (void)hipMemsetAsync(sum, 0, 2 * FH * sizeof(float), stream);
  bn_stats_kernel<<<256, 128, 0, stream>>>(bufB, sum, sumsq, n);
  bn_finalize_kernel<<<1, 128, 0, stream>>>(sum, sumsq, g1, be1, scale, shift, n);
  bn_apply_relu_kernel<<<ceil_div(total4, 256), 256, 0, stream>>>(bufB, scale, shift, total4);

  // --- final layer, commuted: (bufB @ W2) -> bufA[n x 64]; conv+b2 -> d_out ---
  gemm2_kernel<FH, FO, 4><<<gemm_blocks, 256, 0, stream>>>(bufB, W2, nullptr, bufA, n);
  conv_gather4_kernel<FO><<<ceil_div((long long)n * (FO / 16), 256), 256, 0, stream>>>(
      bufA, startA, degc, ep, b2, (float*)d_out, n);
}

// Round 6
// 453.798 us; speedup vs baseline: 9.9574x; 1.0775x over previous
//
#include <hip/hip_runtime.h>
#include <cstdint>

#define F0 100
#define FH 128
#define FO 64
#define NCPY 8
#define BN_EPS 1e-5f

static inline int ceil_div(long long a, long long b) { return (int)((a + b - 1) / b); }

// XCD id (0..7 on MI355X); any value is correct (masked), accurate values give locality.
__device__ __forceinline__ int xcc_copy() {
  int v;
  asm volatile("s_getreg_b32 %0, hwreg(20, 0, 32)" : "=s"(v));
  return v & (NCPY - 1);
}

// ---------------- GEMM body: out[n x F] = A[n x K] @ W[K x F] (+bias, opt BN+relu on A) ----

template <int K, int F, int TM, bool BN_A>
__device__ __forceinline__ void gemm2_body(int bid, const float* __restrict__ A,
                                           const float* __restrict__ W,
                                           const float* __restrict__ bias,
                                           const float* __restrict__ scA,
                                           const float* __restrict__ shA,
                                           float* __restrict__ out, int n) {
  constexpr int NCG = F / 4;
  constexpr int NRG = 256 / NCG;
  constexpr int BR = NRG * TM;
  constexpr int BK = 32;
  constexpr int K4 = K / 4;
  constexpr int F4 = F / 4;

  __shared__ float sW[BK][F];
  __shared__ float sA[BR][BK];

  const int tid = threadIdx.x;
  const int cg = tid % NCG;
  const int rg = tid / NCG;
  const int row0 = bid * BR;

  float4 acc[TM];
#pragma unroll
  for (int t = 0; t < TM; ++t) acc[t] = make_float4(0.f, 0.f, 0.f, 0.f);

  const float4* A4 = (const float4*)A;
  const float4* W4 = (const float4*)W;
  const float4 z4 = make_float4(0.f, 0.f, 0.f, 0.f);

  for (int k0 = 0; k0 < K; k0 += BK) {
    for (int i = tid; i < BK * F4; i += 256) {
      int kk = i / F4, f4 = i % F4;
      int gk = k0 + kk;
      ((float4*)&sW[kk][0])[f4] = (gk < K) ? W4[(size_t)gk * F4 + f4] : z4;
    }
    for (int i = tid; i < BR * (BK / 4); i += 256) {
      int r = i / (BK / 4), k4 = i % (BK / 4);
      int gr = row0 + r;
      int gk = k0 + k4 * 4;
      float4 av = z4;
      if (gr < n && gk + 3 < K) {
        av = A4[(size_t)gr * K4 + (gk >> 2)];
        if (BN_A) {
          float4 sc = ((const float4*)scA)[gk >> 2];
          float4 sh = ((const float4*)shA)[gk >> 2];
          av.x = fmaxf(fmaf(av.x, sc.x, sh.x), 0.f);
          av.y = fmaxf(fmaf(av.y, sc.y, sh.y), 0.f);
          av.z = fmaxf(fmaf(av.z, sc.z, sh.z), 0.f);
          av.w = fmaxf(fmaf(av.w, sc.w, sh.w), 0.f);
        }
      }
      ((float4*)&sA[r][0])[k4] = av;
    }
    __syncthreads();
#pragma unroll 4
    for (int kk = 0; kk < BK; ++kk) {
      float4 w = ((const float4*)&sW[kk][0])[cg];
#pragma unroll
      for (int t = 0; t < TM; ++t) {
        float a = sA[rg * TM + t][kk];
        acc[t].x = fmaf(a, w.x, acc[t].x);
        acc[t].y = fmaf(a, w.y, acc[t].y);
        acc[t].z = fmaf(a, w.z, acc[t].z);
        acc[t].w = fmaf(a, w.w, acc[t].w);
      }
    }
    __syncthreads();
  }

  float4 bb = bias ? ((const float4*)bias)[cg] : z4;
#pragma unroll
  for (int t = 0; t < TM; ++t) {
    int gr = row0 + rg * TM + t;
    if (gr < n) {
      float4 v = acc[t];
      v.x += bb.x; v.y += bb.y; v.z += bb.z; v.w += bb.w;
      ((float4*)out)[(size_t)gr * F4 + cg] = v;
    }
  }
}

template <int K, int F, int TM, bool BN_A>
__global__ __launch_bounds__(256) void gemm2_kernel(const float* __restrict__ A,
                                                    const float* __restrict__ W,
                                                    const float* __restrict__ bias,
                                                    const float* __restrict__ scA,
                                                    const float* __restrict__ shA,
                                                    float* __restrict__ out, int n) {
  gemm2_body<K, F, TM, BN_A>(blockIdx.x, A, W, bias, scA, shA, out, n);
}

// ---------------- fused: gemm0 (x@W0) in parallel with hist_pos ----------------
// gemm blocks striped 1-in-5 so both workloads co-run across CUs.

__global__ __launch_bounds__(256) void fused_gemm_hist_kernel(
    const float* __restrict__ A, const float* __restrict__ W, float* __restrict__ out, int n,
    int GB, const int* __restrict__ row, const int* __restrict__ col,
    int* __restrict__ degr_cp, int* __restrict__ degc_cp, int* __restrict__ posw, int E) {
  int bid = blockIdx.x;
  int r5 = bid % 5;
  int g = bid / 5;
  if (r5 == 0 && g < GB) {
    gemm2_body<F0, FH, 8, false>(g, A, W, nullptr, nullptr, nullptr, out, n);
    return;
  }
  int h = (r5 == 0) ? (bid - GB)  // only possible if g>=GB (tail)
                    : (bid - (g + 1));
  int e = h * 256 + threadIdx.x;
  if (e >= E) return;
  int j = xcc_copy();
  int r = row[e], c = col[e];
  atomicAdd(&degr_cp[(size_t)j * n + r], 1);
  int pos = atomicAdd(&degc_cp[(size_t)j * n + c], 1);
  posw[e] = pos | (j << 28);
}

// ---------------- scan stage 1: reduce copies + dinv + degc + block-exclusive-scan ----

__global__ __launch_bounds__(256) void scan_fused_kernel(const int* __restrict__ degr_cp,
                                                         const int* __restrict__ degc_cp,
                                                         int* __restrict__ degc,
                                                         float* __restrict__ dinv,
                                                         int* __restrict__ startA,
                                                         int* __restrict__ bsums, int n) {
  __shared__ int s[256];
  int i = blockIdx.x * 256 + threadIdx.x;
  int dr = 0, dc = 0;
  if (i < n) {
#pragma unroll
    for (int j = 0; j < NCPY; ++j) {
      dr += degr_cp[(size_t)j * n + i];
      dc += degc_cp[(size_t)j * n + i];
    }
    degc[i] = dc;
    dinv[i] = (dr > 0) ? rsqrtf((float)dr) : 0.0f;
  }
  int v = (i < n) ? dc : 0;
  s[threadIdx.x] = v;
  __syncthreads();
  for (int off = 1; off < 256; off <<= 1) {
    int t = 0;
    if (threadIdx.x >= off) t = s[threadIdx.x - off];
    __syncthreads();
    if (threadIdx.x >= off) s[threadIdx.x] += t;
    __syncthreads();
  }
  if (i < n) startA[i] = s[threadIdx.x] - v;
  if (threadIdx.x == 255) bsums[blockIdx.x] = s[255];
}

__global__ __launch_bounds__(256) void scan_partials_kernel(int* __restrict__ bsums, int nb) {
  __shared__ int s[256];
  int v = (threadIdx.x < nb) ? bsums[threadIdx.x] : 0;
  s[threadIdx.x] = v;
  __syncthreads();
  for (int off = 1; off < 256; off <<= 1) {
    int t = 0;
    if (threadIdx.x >= off) t = s[threadIdx.x - off];
    __syncthreads();
    if (threadIdx.x >= off) s[threadIdx.x] += t;
    __syncthreads();
  }
  if (threadIdx.x < nb) bsums[threadIdx.x] = s[threadIdx.x] - v;
}

// ---------------- scan stage 3: add block offsets + per-copy base offsets ----------------

__global__ __launch_bounds__(256) void scan_add_copyoff_kernel(int* __restrict__ startA,
                                                               const int* __restrict__ bsums,
                                                               const int* __restrict__ degc_cp,
                                                               int* __restrict__ copyOff, int n) {
  int i = blockIdx.x * 256 + threadIdx.x;
  if (i >= n) return;
  int base = startA[i] + bsums[blockIdx.x];
  startA[i] = base;
  int running = base;
#pragma unroll
  for (int j = 0; j < NCPY; ++j) {
    copyOff[(size_t)j * n + i] = running;
    running += degc_cp[(size_t)j * n + i];
  }
}

// ---------------- atomic-free scatter of packed (src, coef) into dst-bucket order --------

__global__ __launch_bounds__(256) void csr_scatter2_kernel(const int* __restrict__ row,
                                                           const int* __restrict__ col,
                                                           const float* __restrict__ ew,
                                                           const float* __restrict__ dinv,
                                                           const int* __restrict__ copyOff,
                                                           const int* __restrict__ posw,
                                                           int2* __restrict__ ep, int E, int n) {
  int e = blockIdx.x * blockDim.x + threadIdx.x;
  if (e >= E) return;
  int r = row[e], c = col[e];
  int pw = posw[e];
  int j = pw >> 28;
  int pos = copyOff[(size_t)j * n + c] + (pw & 0x0FFFFFFF);
  float coef = dinv[r] * ew[e] * dinv[c];
  ep[pos] = make_int2(r, __float_as_int(coef));
}

// ---------------- conv gather, 4 float4/thread; optional fused BN+relu on loads ----------

template <int F, bool DO_BN>
__global__ __launch_bounds__(256) void conv_gather4_kernel(const float* __restrict__ x,
                                                           const int* __restrict__ startA,
                                                           const int* __restrict__ degc,
                                                           const int2* __restrict__ ep,
                                                           const float* __restrict__ bias,
                                                           const float* __restrict__ scale,
                                                           const float* __restrict__ shift,
                                                           float* __restrict__ out, int n) {
  constexpr int G = F / 4;    // float4 groups per row
  constexpr int TPD = G / 4;  // threads per dst (4 float4 each)
  long long tid = (long long)blockIdx.x * 256 + threadIdx.x;
  if (tid >= (long long)n * TPD) return;
  int dst = (int)(tid / TPD);
  int q = (int)(tid % TPD);
  int s0 = startA[dst];
  int d = degc[dst];
  const float4* x4 = (const float4*)x;
  float4 sc0v, sc1v, sc2v, sc3v, sh0v, sh1v, sh2v, sh3v;
  if (DO_BN) {
    const float4* sc4 = (const float4*)scale + q;
    const float4* sh4 = (const float4*)shift + q;
    sc0v = sc4[0]; sc1v = sc4[TPD]; sc2v = sc4[2 * TPD]; sc3v = sc4[3 * TPD];
    sh0v = sh4[0]; sh1v = sh4[TPD]; sh2v = sh4[2 * TPD]; sh3v = sh4[3 * TPD];
  }
  float4 a0 = make_float4(0.f, 0.f, 0.f, 0.f), a1 = a0, a2 = a0, a3 = a0;
  for (int k = 0; k < d; ++k) {
    int2 e = ep[s0 + k];
    float c = __int_as_float(e.y);
    const float4* xp = x4 + (size_t)e.x * G + q;
    float4 v0 = xp[0], v1 = xp[TPD], v2 = xp[2 * TPD], v3 = xp[3 * TPD];
    if (DO_BN) {
      v0.x = fmaxf(fmaf(v0.x, sc0v.x, sh0v.x), 0.f); v0.y = fmaxf(fmaf(v0.y, sc0v.y, sh0v.y), 0.f);
      v0.z = fmaxf(fmaf(v0.z, sc0v.z, sh0v.z), 0.f); v0.w = fmaxf(fmaf(v0.w, sc0v.w, sh0v.w), 0.f);
      v1.x = fmaxf(fmaf(v1.x, sc1v.x, sh1v.x), 0.f); v1.y = fmaxf(fmaf(v1.y, sc1v.y, sh1v.y), 0.f);
      v1.z = fmaxf(fmaf(v1.z, sc1v.z, sh1v.z), 0.f); v1.w = fmaxf(fmaf(v1.w, sc1v.w, sh1v.w), 0.f);
      v2.x = fmaxf(fmaf(v2.x, sc2v.x, sh2v.x), 0.f); v2.y = fmaxf(fmaf(v2.y, sc2v.y, sh2v.y), 0.f);
      v2.z = fmaxf(fmaf(v2.z, sc2v.z, sh2v.z), 0.f); v2.w = fmaxf(fmaf(v2.w, sc2v.w, sh2v.w), 0.f);
      v3.x = fmaxf(fmaf(v3.x, sc3v.x, sh3v.x), 0.f); v3.y = fmaxf(fmaf(v3.y, sc3v.y, sh3v.y), 0.f);
      v3.z = fmaxf(fmaf(v3.z, sc3v.z, sh3v.z), 0.f); v3.w = fmaxf(fmaf(v3.w, sc3v.w, sh3v.w), 0.f);
    }
    a0.x = fmaf(c, v0.x, a0.x); a0.y = fmaf(c, v0.y, a0.y);
    a0.z = fmaf(c, v0.z, a0.z); a0.w = fmaf(c, v0.w, a0.w);
    a1.x = fmaf(c, v1.x, a1.x); a1.y = fmaf(c, v1.y, a1.y);
    a1.z = fmaf(c, v1.z, a1.z); a1.w = fmaf(c, v1.w, a1.w);
    a2.x = fmaf(c, v2.x, a2.x); a2.y = fmaf(c, v2.y, a2.y);
    a2.z = fmaf(c, v2.z, a2.z); a2.w = fmaf(c, v2.w, a2.w);
    a3.x = fmaf(c, v3.x, a3.x); a3.y = fmaf(c, v3.y, a3.y);
    a3.z = fmaf(c, v3.z, a3.z); a3.w = fmaf(c, v3.w, a3.w);
  }
  float4* o4 = (float4*)out + (size_t)dst * G + q;
  if (bias) {
    const float4* b4 = (const float4*)bias + q;
    float4 b0v = b4[0], b1v = b4[TPD], b2v = b4[2 * TPD], b3v = b4[3 * TPD];
    a0.x += b0v.x; a0.y += b0v.y; a0.z += b0v.z; a0.w += b0v.w;
    a1.x += b1v.x; a1.y += b1v.y; a1.z += b1v.z; a1.w += b1v.w;
    a2.x += b2v.x; a2.y += b2v.y; a2.z += b2v.z; a2.w += b2v.w;
    a3.x += b3v.x; a3.y += b3v.y; a3.z += b3v.z; a3.w += b3v.w;
  }
  o4[0] = a0; o4[TPD] = a1; o4[2 * TPD] = a2; o4[3 * TPD] = a3;
}

// ---------------- BatchNorm stats / finalize ----------------

__global__ __launch_bounds__(128) void bn_stats_kernel(const float* __restrict__ z,
                                                       float* __restrict__ sum,
                                                       float* __restrict__ sumsq, int n) {
  int f = threadIdx.x;
  float s = 0.0f, s2 = 0.0f;
  for (int r = blockIdx.x; r < n; r += gridDim.x) {
    float v = z[(size_t)r * FH + f];
    s += v;
    s2 += v * v;
  }
  unsafeAtomicAdd(&sum[f], s);
  unsafeAtomicAdd(&sumsq[f], s2);
}

__global__ __launch_bounds__(128) void bn_finalize_kernel(const float* __restrict__ sum,
                                                          const float* __restrict__ sumsq,
                                                          const float* __restrict__ g,
                                                          const float* __restrict__ be,
                                                          float* __restrict__ scale,
                                                          float* __restrict__ shift, int n) {
  int f = threadIdx.x;
  float invN = 1.0f / (float)n;
  float mean = sum[f] * invN;
  float var = sumsq[f] * invN - mean * mean;
  var = fmaxf(var, 0.0f);
  float sc = g[f] / sqrtf(var + BN_EPS);
  scale[f] = sc;
  shift[f] = be[f] - mean * sc;
}

// ---------------- launch ----------------

extern "C" void kernel_launch(void* const* d_in, const int* in_sizes, int n_in,
                              void* d_out, int out_size, void* d_ws, size_t ws_size,
                              hipStream_t stream) {
  const float* x   = (const float*)d_in[0];
  const int*   ei  = (const int*)d_in[1];
  const float* ew  = (const float*)d_in[2];
  const float* W0  = (const float*)d_in[3];
  const float* b0  = (const float*)d_in[4];
  const float* g0  = (const float*)d_in[5];
  const float* be0 = (const float*)d_in[6];
  const float* W1  = (const float*)d_in[7];
  const float* b1  = (const float*)d_in[8];
  const float* g1  = (const float*)d_in[9];
  const float* be1 = (const float*)d_in[10];
  const float* W2  = (const float*)d_in[11];
  const float* b2  = (const float*)d_in[12];

  const int n = in_sizes[0] / F0;
  const int E = in_sizes[2];
  const int* row = ei;
  const int* col = ei + E;

  // persistent workspace
  float* bufA   = (float*)d_ws;                      // n*FH floats (written by fused gemm0!)
  float* bufB   = bufA + (size_t)n * FH;             // n*FH floats
  int2*  ep     = (int2*)(bufB + (size_t)n * FH);    // E int2
  int*   degc   = (int*)(ep + E);                    // n ints
  int*   startA = degc + n;                          // n ints
  float* dinv   = (float*)(startA + n);              // n floats
  int*   bsums  = (int*)(dinv + n);                  // 256 ints
  float* sum    = (float*)(bsums + 256);             // 128
  float* sumsq  = sum + FH;                          // 128
  float* scale  = sumsq + FH;                        // 128
  float* shift  = scale + FH;                        // 128
  // CSR-build transients aliased into bufB (bufB first written by conv0, after scatter)
  int*   posw    = (int*)bufB;                       // E ints
  int*   degr_cp = posw + E;                         // NCPY*n ints (zeroed with degc_cp)
  int*   degc_cp = degr_cp + (size_t)NCPY * n;       // NCPY*n ints
  int*   copyOff = degc_cp + (size_t)NCPY * n;       // NCPY*n ints

  const int nb = ceil_div(n, 256);
  const int GB = ceil_div(n, 64);          // gemm blocks (BR=64)
  const int HB = ceil_div(E, 256);         // hist blocks

  // --- K1: zero copies, then fused {gemm0: x@W0 -> bufA} || {hist_pos} ---
  (void)hipMemsetAsync(degr_cp, 0, 2 * (size_t)NCPY * n * sizeof(int), stream);
  fused_gemm_hist_kernel<<<GB + HB, 256, 0, stream>>>(x, W0, bufA, n, GB, row, col,
                                                      degr_cp, degc_cp, posw, E);
  // --- CSR build ---
  scan_fused_kernel<<<nb, 256, 0, stream>>>(degr_cp, degc_cp, degc, dinv, startA, bsums, n);
  scan_partials_kernel<<<1, 256, 0, stream>>>(bsums, nb);
  scan_add_copyoff_kernel<<<nb, 256, 0, stream>>>(startA, bsums, degc_cp, copyOff, n);
  csr_scatter2_kernel<<<HB, 256, 0, stream>>>(row, col, ew, dinv, copyOff, posw, ep, E, n);

  // --- layer 0 tail: z0 = conv(bufA)+b0 -> bufB; stats0 ---
  conv_gather4_kernel<FH, false><<<ceil_div((long long)n * (FH / 16), 256), 256, 0, stream>>>(
      bufA, startA, degc, ep, b0, nullptr, nullptr, bufB, n);
  (void)hipMemsetAsync(sum, 0, 2 * FH * sizeof(float), stream);
  bn_stats_kernel<<<256, 128, 0, stream>>>(bufB, sum, sumsq, n);
  bn_finalize_kernel<<<1, 128, 0, stream>>>(sum, sumsq, g0, be0, scale, shift, n);

  // --- layer 1: conv(relu(bn0(z0))) -> bufA (BN fused in loads); gemm W1+b1 -> bufB(z1) ---
  conv_gather4_kernel<FH, true><<<ceil_div((long long)n * (FH / 16), 256), 256, 0, stream>>>(
      bufB, startA, degc, ep, nullptr, scale, shift, bufA, n);
  gemm2_kernel<FH, FH, 8, false><<<GB, 256, 0, stream>>>(bufA, W1, b1, nullptr, nullptr, bufB, n);
  (void)hipMemsetAsync(sum, 0, 2 * FH * sizeof(float), stream);
  bn_stats_kernel<<<256, 128, 0, stream>>>(bufB, sum, sumsq, n);
  bn_finalize_kernel<<<1, 128, 0, stream>>>(sum, sumsq, g1, be1, scale, shift, n);

  // --- final layer (commuted): t2 = relu(bn1(z1)) @ W2 -> bufA (BN fused in staging);
  //     out = conv(t2) + b2 ---
  gemm2_kernel<FH, FO, 4, true><<<GB, 256, 0, stream>>>(bufB, W2, nullptr, scale, shift, bufA, n);
  conv_gather4_kernel<FO, false><<<ceil_div((long long)n * (FO / 16), 256), 256, 0, stream>>>(
      bufA, startA, degc, ep, b2, nullptr, nullptr, (float*)d_out, n);
}

// Round 7
// 390.778 us; speedup vs baseline: 11.5632x; 1.1613x over previous
//
#include <hip/hip_runtime.h>
#include <cstdint>

#define F0 100
#define FH 128
#define FO 64
#define BN_EPS 1e-5f

typedef unsigned short ushort_t;
typedef unsigned int uint_t;

static inline int ceil_div(long long a, long long b) { return (int)((a + b - 1) / b); }

// ---- bf16 helpers (fp32 math everywhere; bf16 is storage only) ----
__device__ __forceinline__ float bf_lo(uint_t w) { return __uint_as_float(w << 16); }
__device__ __forceinline__ float bf_hi(uint_t w) { return __uint_as_float(w & 0xffff0000u); }
__device__ __forceinline__ uint_t f2bf(float f) {  // RNE
  uint_t u = __float_as_uint(f);
  return (u + 0x7fffu + ((u >> 16) & 1u)) >> 16;
}
__device__ __forceinline__ uint_t pack2(float a, float b) {
  return f2bf(a) | (f2bf(b) << 16);
}

// ---------------- GEMM body: out[n x F] = A[n x K] @ W[K x F] (+bias / BN+relu on A) ----
// A: fp32 or bf16 (A_BF16); out: fp32 or bf16 (OUT_BF16). Math fp32.

template <int K, int F, int TM, bool BN_A, bool A_BF16, bool OUT_BF16>
__device__ __forceinline__ void gemm2_body(int bid, const void* __restrict__ A_,
                                           const float* __restrict__ W,
                                           const float* __restrict__ bias,
                                           const float* __restrict__ scA,
                                           const float* __restrict__ shA,
                                           void* __restrict__ out_, int n) {
  constexpr int NCG = F / 4;
  constexpr int NRG = 256 / NCG;
  constexpr int BR = NRG * TM;
  constexpr int BK = 32;
  constexpr int F4 = F / 4;

  __shared__ float sW[BK][F];
  __shared__ float sA[BR][BK];

  const int tid = threadIdx.x;
  const int cg = tid % NCG;
  const int rg = tid / NCG;
  const int row0 = bid * BR;

  float4 acc[TM];
#pragma unroll
  for (int t = 0; t < TM; ++t) acc[t] = make_float4(0.f, 0.f, 0.f, 0.f);

  const float4* W4 = (const float4*)W;
  const float4 z4 = make_float4(0.f, 0.f, 0.f, 0.f);

  for (int k0 = 0; k0 < K; k0 += BK) {
    for (int i = tid; i < BK * F4; i += 256) {
      int kk = i / F4, f4 = i % F4;
      int gk = k0 + kk;
      ((float4*)&sW[kk][0])[f4] = (gk < K) ? W4[(size_t)gk * F4 + f4] : z4;
    }
    for (int i = tid; i < BR * (BK / 4); i += 256) {
      int r = i / (BK / 4), k4 = i % (BK / 4);
      int gr = row0 + r;
      int gk = k0 + k4 * 4;
      float4 av = z4;
      if (gr < n && gk + 3 < K) {
        if (A_BF16) {
          uint2 u = ((const uint2*)A_)[(size_t)gr * (K / 4) + (gk >> 2)];
          av.x = bf_lo(u.x); av.y = bf_hi(u.x);
          av.z = bf_lo(u.y); av.w = bf_hi(u.y);
        } else {
          av = ((const float4*)A_)[(size_t)gr * (K / 4) + (gk >> 2)];
        }
        if (BN_A) {
          float4 sc = ((const float4*)scA)[gk >> 2];
          float4 sh = ((const float4*)shA)[gk >> 2];
          av.x = fmaxf(fmaf(av.x, sc.x, sh.x), 0.f);
          av.y = fmaxf(fmaf(av.y, sc.y, sh.y), 0.f);
          av.z = fmaxf(fmaf(av.z, sc.z, sh.z), 0.f);
          av.w = fmaxf(fmaf(av.w, sc.w, sh.w), 0.f);
        }
      }
      ((float4*)&sA[r][0])[k4] = av;
    }
    __syncthreads();
#pragma unroll 4
    for (int kk = 0; kk < BK; ++kk) {
      float4 w = ((const float4*)&sW[kk][0])[cg];
#pragma unroll
      for (int t = 0; t < TM; ++t) {
        float a = sA[rg * TM + t][kk];
        acc[t].x = fmaf(a, w.x, acc[t].x);
        acc[t].y = fmaf(a, w.y, acc[t].y);
        acc[t].z = fmaf(a, w.z, acc[t].z);
        acc[t].w = fmaf(a, w.w, acc[t].w);
      }
    }
    __syncthreads();
  }

  float4 bb = bias ? ((const float4*)bias)[cg] : z4;
#pragma unroll
  for (int t = 0; t < TM; ++t) {
    int gr = row0 + rg * TM + t;
    if (gr < n) {
      float4 v = acc[t];
      v.x += bb.x; v.y += bb.y; v.z += bb.z; v.w += bb.w;
      if (OUT_BF16) {
        ((uint2*)out_)[(size_t)gr * F4 + cg] = make_uint2(pack2(v.x, v.y), pack2(v.z, v.w));
      } else {
        ((float4*)out_)[(size_t)gr * F4 + cg] = v;
      }
    }
  }
}

template <int K, int F, int TM, bool BN_A, bool A_BF16, bool OUT_BF16>
__global__ __launch_bounds__(256) void gemm2_kernel(const void* __restrict__ A,
                                                    const float* __restrict__ W,
                                                    const float* __restrict__ bias,
                                                    const float* __restrict__ scA,
                                                    const float* __restrict__ shA,
                                                    void* __restrict__ out, int n) {
  gemm2_body<K, F, TM, BN_A, A_BF16, OUT_BF16>(blockIdx.x, A, W, bias, scA, shA, out, n);
}

// ---------------- fused: gemm0 (x@W0 -> bf16) in parallel with single-copy hist ----------

__global__ __launch_bounds__(256) void fused_gemm_hist_kernel(
    const float* __restrict__ A, const float* __restrict__ W, void* __restrict__ out, int n,
    int GB, const int* __restrict__ row, const int* __restrict__ col,
    int* __restrict__ degr, int* __restrict__ degc, int* __restrict__ posw, int E) {
  int bid = blockIdx.x;
  int r5 = bid % 5;
  int g = bid / 5;
  if (r5 == 0 && g < GB) {
    gemm2_body<F0, FH, 8, false, false, true>(g, A, W, nullptr, nullptr, nullptr, out, n);
    return;
  }
  int h = (r5 == 0) ? (bid - GB) : (bid - (g + 1));
  int e = h * 256 + threadIdx.x;
  if (e >= E) return;
  int r = row[e], c = col[e];
  atomicAdd(&degr[r], 1);
  int pos = atomicAdd(&degc[c], 1);
  posw[e] = pos;
}

// ---------------- scan stage 1: dinv + block-exclusive-scan of degc ----------------

__global__ __launch_bounds__(256) void scan_fused_kernel(const int* __restrict__ degr,
                                                         const int* __restrict__ degc,
                                                         float* __restrict__ dinv,
                                                         int* __restrict__ startA,
                                                         int* __restrict__ bsums, int n) {
  __shared__ int s[256];
  int i = blockIdx.x * 256 + threadIdx.x;
  int dc = 0;
  if (i < n) {
    int dr = degr[i];
    dc = degc[i];
    dinv[i] = (dr > 0) ? rsqrtf((float)dr) : 0.0f;
  }
  s[threadIdx.x] = dc;
  __syncthreads();
  for (int off = 1; off < 256; off <<= 1) {
    int t = 0;
    if (threadIdx.x >= off) t = s[threadIdx.x - off];
    __syncthreads();
    if (threadIdx.x >= off) s[threadIdx.x] += t;
    __syncthreads();
  }
  if (i < n) startA[i] = s[threadIdx.x] - dc;
  if (threadIdx.x == 255) bsums[blockIdx.x] = s[255];
}

__global__ __launch_bounds__(256) void scan_partials_kernel(int* __restrict__ bsums, int nb) {
  __shared__ int s[256];
  int v = (threadIdx.x < nb) ? bsums[threadIdx.x] : 0;
  s[threadIdx.x] = v;
  __syncthreads();
  for (int off = 1; off < 256; off <<= 1) {
    int t = 0;
    if (threadIdx.x >= off) t = s[threadIdx.x - off];
    __syncthreads();
    if (threadIdx.x >= off) s[threadIdx.x] += t;
    __syncthreads();
  }
  if (threadIdx.x < nb) bsums[threadIdx.x] = s[threadIdx.x] - v;
}

__global__ __launch_bounds__(256) void scan_add_kernel(int* __restrict__ startA,
                                                       const int* __restrict__ bsums, int n) {
  int i = blockIdx.x * 256 + threadIdx.x;
  if (i < n) startA[i] += bsums[blockIdx.x];
}

// ---------------- atomic-free scatter of packed (src, coef) into dst-bucket order --------

__global__ __launch_bounds__(256) void csr_scatter2_kernel(const int* __restrict__ row,
                                                           const int* __restrict__ col,
                                                           const float* __restrict__ ew,
                                                           const float* __restrict__ dinv,
                                                           const int* __restrict__ startA,
                                                           const int* __restrict__ posw,
                                                           int2* __restrict__ ep, int E) {
  int e = blockIdx.x * blockDim.x + threadIdx.x;
  if (e >= E) return;
  int r = row[e], c = col[e];
  int pos = startA[c] + posw[e];
  float coef = dinv[r] * ew[e] * dinv[c];
  ep[pos] = make_int2(r, __float_as_int(coef));
}

// ---------------- conv gather on bf16 input: out[dst] = bias + sum coef * f(x[src]) ------
// Thread = (dst, q): 2 uint4 chunks (16 features). Optional BN+relu on loads.
// OUT_F32: fp32 output (final layer), else bf16.

template <int F, bool DO_BN, bool OUT_F32>
__global__ __launch_bounds__(256) void conv_bf16_kernel(const ushort_t* __restrict__ x,
                                                        const int* __restrict__ startA,
                                                        const int* __restrict__ degc,
                                                        const int2* __restrict__ ep,
                                                        const float* __restrict__ bias,
                                                        const float* __restrict__ scale,
                                                        const float* __restrict__ shift,
                                                        void* __restrict__ out, int n) {
  constexpr int G2 = F / 8;    // uint4 (8 bf16) groups per row
  constexpr int TPD = G2 / 2;  // threads per dst (2 chunks each)
  long long tid = (long long)blockIdx.x * 256 + threadIdx.x;
  if (tid >= (long long)n * TPD) return;
  int dst = (int)(tid / TPD);
  int q = (int)(tid % TPD);
  int s0 = startA[dst];
  int d = degc[dst];
  const uint4* x4 = (const uint4*)x;

  float sc[16], sh[16];
  if (DO_BN) {
#pragma unroll
    for (int ch = 0; ch < 2; ++ch) {
      int g = q + ch * TPD;
#pragma unroll
      for (int j = 0; j < 8; ++j) {
        sc[ch * 8 + j] = scale[g * 8 + j];
        sh[ch * 8 + j] = shift[g * 8 + j];
      }
    }
  }

  float acc[16];
#pragma unroll
  for (int j = 0; j < 16; ++j) acc[j] = 0.f;

  for (int k = 0; k < d; ++k) {
    int2 e = ep[s0 + k];
    float c = __int_as_float(e.y);
    const uint4* xp = x4 + (size_t)e.x * G2 + q;
    uint4 v0 = xp[0];
    uint4 v1 = xp[TPD];
    uint_t vv[8] = {v0.x, v0.y, v0.z, v0.w, v1.x, v1.y, v1.z, v1.w};
#pragma unroll
    for (int h = 0; h < 8; ++h) {
      float f0 = bf_lo(vv[h]);
      float f1 = bf_hi(vv[h]);
      if (DO_BN) {
        f0 = fmaxf(fmaf(f0, sc[2 * h], sh[2 * h]), 0.f);
        f1 = fmaxf(fmaf(f1, sc[2 * h + 1], sh[2 * h + 1]), 0.f);
      }
      acc[2 * h] = fmaf(c, f0, acc[2 * h]);
      acc[2 * h + 1] = fmaf(c, f1, acc[2 * h + 1]);
    }
  }

  if (bias) {
#pragma unroll
    for (int ch = 0; ch < 2; ++ch) {
      int g = q + ch * TPD;
#pragma unroll
      for (int j = 0; j < 8; ++j) acc[ch * 8 + j] += bias[g * 8 + j];
    }
  }

  if (OUT_F32) {
    float4* o4 = (float4*)out;
    size_t base = (size_t)dst * (F / 4);
    o4[base + 2 * q] = make_float4(acc[0], acc[1], acc[2], acc[3]);
    o4[base + 2 * q + 1] = make_float4(acc[4], acc[5], acc[6], acc[7]);
    o4[base + 2 * (q + TPD)] = make_float4(acc[8], acc[9], acc[10], acc[11]);
    o4[base + 2 * (q + TPD) + 1] = make_float4(acc[12], acc[13], acc[14], acc[15]);
  } else {
    uint4* o4 = (uint4*)out;
    size_t base = (size_t)dst * G2;
    o4[base + q] = make_uint4(pack2(acc[0], acc[1]), pack2(acc[2], acc[3]),
                              pack2(acc[4], acc[5]), pack2(acc[6], acc[7]));
    o4[base + q + TPD] = make_uint4(pack2(acc[8], acc[9]), pack2(acc[10], acc[11]),
                                    pack2(acc[12], acc[13]), pack2(acc[14], acc[15]));
  }
}

// ---------------- BatchNorm stats (bf16 input) / finalize ----------------

__global__ __launch_bounds__(128) void bn_stats_bf16_kernel(const ushort_t* __restrict__ z,
                                                            float* __restrict__ sum,
                                                            float* __restrict__ sumsq, int n) {
  int f = threadIdx.x;
  float s = 0.0f, s2 = 0.0f;
  for (int r = blockIdx.x; r < n; r += gridDim.x) {
    float v = __uint_as_float(((uint_t)z[(size_t)r * FH + f]) << 16);
    s += v;
    s2 += v * v;
  }
  unsafeAtomicAdd(&sum[f], s);
  unsafeAtomicAdd(&sumsq[f], s2);
}

__global__ __launch_bounds__(128) void bn_finalize_kernel(const float* __restrict__ sum,
                                                          const float* __restrict__ sumsq,
                                                          const float* __restrict__ g,
                                                          const float* __restrict__ be,
                                                          float* __restrict__ scale,
                                                          float* __restrict__ shift, int n) {
  int f = threadIdx.x;
  float invN = 1.0f / (float)n;
  float mean = sum[f] * invN;
  float var = sumsq[f] * invN - mean * mean;
  var = fmaxf(var, 0.0f);
  float sc = g[f] / sqrtf(var + BN_EPS);
  scale[f] = sc;
  shift[f] = be[f] - mean * sc;
}

// ---------------- launch ----------------

extern "C" void kernel_launch(void* const* d_in, const int* in_sizes, int n_in,
                              void* d_out, int out_size, void* d_ws, size_t ws_size,
                              hipStream_t stream) {
  const float* x   = (const float*)d_in[0];
  const int*   ei  = (const int*)d_in[1];
  const float* ew  = (const float*)d_in[2];
  const float* W0  = (const float*)d_in[3];
  const float* b0  = (const float*)d_in[4];
  const float* g0  = (const float*)d_in[5];
  const float* be0 = (const float*)d_in[6];
  const float* W1  = (const float*)d_in[7];
  const float* b1  = (const float*)d_in[8];
  const float* g1  = (const float*)d_in[9];
  const float* be1 = (const float*)d_in[10];
  const float* W2  = (const float*)d_in[11];
  const float* b2  = (const float*)d_in[12];

  const int n = in_sizes[0] / F0;
  const int E = in_sizes[2];
  const int* row = ei;
  const int* col = ei + E;

  // workspace layout (bf16 node buffers)
  ushort_t* bufA  = (ushort_t*)d_ws;                    // n*FH bf16 (12.8 MB)
  ushort_t* bufB  = bufA + (size_t)n * FH;              // n*FH bf16
  int2*   ep      = (int2*)(bufB + (size_t)n * FH);     // E int2
  int*    degc    = (int*)(ep + E);                     // n ints (memset w/ degr)
  int*    degr    = degc + n;                           // n ints
  int*    startA  = degr + n;                           // n ints
  float*  dinv    = (float*)(startA + n);               // n floats
  int*    bsums   = (int*)(dinv + n);                   // 256 ints
  float*  sum0    = (float*)(bsums + 256);              // 4*128 (memset together)
  float*  sumsq0  = sum0 + FH;
  float*  sum1    = sumsq0 + FH;
  float*  sumsq1  = sum1 + FH;
  float*  scale0  = sumsq1 + FH;
  float*  shift0  = scale0 + FH;
  float*  scale1  = shift0 + FH;
  float*  shift1  = scale1 + FH;
  // transient: posw aliases bufB (bufB first written by conv0, after scatter consumed posw)
  int*    posw    = (int*)bufB;                         // E ints

  const int nb = ceil_div(n, 256);
  const int GB = ceil_div(n, 64);   // gemm blocks (BR=64)
  const int HB = ceil_div(E, 256);  // hist blocks
  const int CB_H = ceil_div((long long)n * (FH / 16), 256);  // conv blocks F=128 (TPD=8)
  const int CB_O = ceil_div((long long)n * (FO / 16), 256);  // conv blocks F=64  (TPD=4)

  // --- K1: zero counters/stats, then fused {gemm0: x@W0 -> bufA bf16} || {hist} ---
  (void)hipMemsetAsync(degc, 0, 2 * (size_t)n * sizeof(int), stream);
  (void)hipMemsetAsync(sum0, 0, 4 * FH * sizeof(float), stream);
  fused_gemm_hist_kernel<<<GB + HB, 256, 0, stream>>>(x, W0, bufA, n, GB, row, col,
                                                      degr, degc, posw, E);
  // --- CSR build ---
  scan_fused_kernel<<<nb, 256, 0, stream>>>(degr, degc, dinv, startA, bsums, n);
  scan_partials_kernel<<<1, 256, 0, stream>>>(bsums, nb);
  scan_add_kernel<<<nb, 256, 0, stream>>>(startA, bsums, n);
  csr_scatter2_kernel<<<HB, 256, 0, stream>>>(row, col, ew, dinv, startA, posw, ep, E);

  // --- layer 0 tail: z0 = conv(bufA) + b0 -> bufB (bf16); stats0 ---
  conv_bf16_kernel<FH, false, false><<<CB_H, 256, 0, stream>>>(
      bufA, startA, degc, ep, b0, nullptr, nullptr, bufB, n);
  bn_stats_bf16_kernel<<<256, 128, 0, stream>>>(bufB, sum0, sumsq0, n);
  bn_finalize_kernel<<<1, 128, 0, stream>>>(sum0, sumsq0, g0, be0, scale0, shift0, n);

  // --- layer 1: conv(relu(bn0(z0))) -> bufA (bf16, BN fused on loads);
  //     gemm W1 + b1 -> bufB (z1 bf16); stats1 ---
  conv_bf16_kernel<FH, true, false><<<CB_H, 256, 0, stream>>>(
      bufB, startA, degc, ep, nullptr, scale0, shift0, bufA, n);
  gemm2_kernel<FH, FH, 8, false, true, true><<<GB, 256, 0, stream>>>(
      bufA, W1, b1, nullptr, nullptr, bufB, n);
  bn_stats_bf16_kernel<<<256, 128, 0, stream>>>(bufB, sum1, sumsq1, n);
  bn_finalize_kernel<<<1, 128, 0, stream>>>(sum1, sumsq1, g1, be1, scale1, shift1, n);

  // --- final layer (commuted): t2 = relu(bn1(z1)) @ W2 -> bufA (bf16, BN fused in staging);
  //     out = conv(t2) + b2 -> d_out (fp32) ---
  gemm2_kernel<FH, FO, 4, true, true, true><<<GB, 256, 0, stream>>>(
      bufB, W2, nullptr, scale1, shift1, bufA, n);
  conv_bf16_kernel<FO, false, true><<<CB_O, 256, 0, stream>>>(
      bufA, startA, degc, ep, b2, nullptr, nullptr, (float*)d_out, n);
}